// Round 8
// baseline (268.106 us; speedup 1.0000x reference)
//
#include <hip/hip_runtime.h>
#include <hip/hip_fp16.h>

// Problem constants
#define B_ 64
#define SW_ 132                 // stored k2 rows: [0,128] real + [129,131] zero pad
#define SIMG_ (256 * SW_)       // 33792 packed half2 per channel plane
#define TIMG_ (3 * SIMG_)       // per batch item per tensor
#define TELEMS_ ((size_t)B_ * TIMG_)

__device__ __forceinline__ float2 cmul(float2 a, float2 b) {
  return make_float2(a.x * b.x - a.y * b.y, a.x * b.y + a.y * b.x);
}
__device__ __forceinline__ unsigned f2u(float2 v) {
  __half2 h = __float22half2_rn(v);
  return __builtin_bit_cast(unsigned, h);
}
__device__ __forceinline__ float2 u2f(unsigned u) {
  return __half22float2(__builtin_bit_cast(__half2, u));
}
// fp8 e4m3 pack/unpack (complex -> 2 bytes). HI must be a compile-time
// constant: the builtin encodes the destination half-word as an immediate.
template <bool HI>
__device__ __forceinline__ unsigned pk8(float2 v, unsigned old) {
  return (unsigned)__builtin_amdgcn_cvt_pk_fp8_f32(v.x, v.y, (int)old, HI);
}
__device__ __forceinline__ float2 up8(unsigned v) {
  return make_float2(__builtin_amdgcn_cvt_f32_fp8((int)v, 0),
                     __builtin_amdgcn_cvt_f32_fp8((int)v, 1));
}

// radix-4 DIF butterfly on 4 slots (intra-lane), optional twiddles
__device__ __forceinline__ void bfly4(float2 x[4], float2 ta, float2 tb, float2 tc, bool tw) {
  float2 a = make_float2(x[0].x + x[2].x, x[0].y + x[2].y);
  float2 b = make_float2(x[0].x - x[2].x, x[0].y - x[2].y);
  float2 c = make_float2(x[1].x + x[3].x, x[1].y + x[3].y);
  float2 d = make_float2(x[1].x - x[3].x, x[1].y - x[3].y);
  float2 y1 = make_float2(b.x + d.y, b.y - d.x);   // b - i d
  float2 y2 = make_float2(a.x - c.x, a.y - c.y);
  float2 y3 = make_float2(b.x - d.y, b.y + d.x);   // b + i d
  x[0] = make_float2(a.x + c.x, a.y + c.y);
  if (tw) { y1 = cmul(y1, ta); y2 = cmul(y2, tb); y3 = cmul(y3, tc); }
  x[1] = y1; x[2] = y2; x[3] = y3;
}

// swap slot bit (pair A=bit0, B=bit1) with lane bit `bit`
__device__ __forceinline__ void xbit(unsigned& A, unsigned& B, int bit, int r) {
  bool hi = (r >> bit) & 1;
  int send = hi ? (int)A : (int)B;
  int got = __shfl_xor(send, 1 << bit, 64);
  if (hi) A = (unsigned)got; else B = (unsigned)got;
}
__device__ __forceinline__ void xdigit(unsigned u[4], int bit, int r) {
  xbit(u[0], u[1], bit, r);
  xbit(u[2], u[3], bit, r);
  xbit(u[0], u[2], bit + 1, r);
  xbit(u[1], u[3], bit + 1, r);
}

// 256-pt radix-4 DIF FFT, register-resident, one wave. Input x[4] fp32 with
// slot = d3 (element e = r + 64*slot). Output packed fp16 in u[4]:
// lane r slot s holds X[k], k = 64*s + m(r), m = 16*(r&3)+4*((r>>2)&3)+(r>>4).
__device__ __forceinline__ void fft256_reg(float2 x[4], unsigned u[4], int r,
                                           const float2 tw[9]) {
  bfly4(x, tw[0], tw[1], tw[2], true);
#pragma unroll
  for (int s = 0; s < 4; ++s) u[s] = f2u(x[s]);
  xdigit(u, 4, r);                                  // d3 <-> d2
#pragma unroll
  for (int s = 0; s < 4; ++s) x[s] = u2f(u[s]);
  bfly4(x, tw[3], tw[4], tw[5], true);
#pragma unroll
  for (int s = 0; s < 4; ++s) u[s] = f2u(x[s]);
  xdigit(u, 2, r);                                  // d2 <-> d1
#pragma unroll
  for (int s = 0; s < 4; ++s) x[s] = u2f(u[s]);
  bfly4(x, tw[6], tw[7], tw[8], true);
#pragma unroll
  for (int s = 0; s < 4; ++s) u[s] = f2u(x[s]);
  xdigit(u, 0, r);                                  // d1 <-> d0
#pragma unroll
  for (int s = 0; s < 4; ++s) x[s] = u2f(u[s]);
  bfly4(x, tw[0], tw[0], tw[0], false);
#pragma unroll
  for (int s = 0; s < 4; ++s) u[s] = f2u(x[s]);
}

// Fused 2D FFT per channel plane: 576 blocks x 1024 thr (16 waves), one
// __syncthreads. S in fp8 e4m3: 128 rows x 128 dwords = 65536 B -> 2 blk/CU.
// Row 0 of S packs the two real spectra rows (k2=0, k2=128) as one complex.
__global__ __launch_bounds__(1024, 8) void fft2_fused(const float* __restrict__ a,
                                                      const float* __restrict__ p,
                                                      const float* __restrict__ n,
                                                      unsigned* __restrict__ outbase) {
  __shared__ unsigned S32[128 * 128];  // 65536 B exactly

  int tid = threadIdx.x;
  int wv = tid >> 6;
  int r = tid & 63;
  int tensor = blockIdx.x / 192;
  int plane = blockIdx.x % 192;
  const float* in = (tensor == 0 ? a : (tensor == 1 ? p : n)) + (size_t)plane * 65536;
  unsigned* outp = outbase + (size_t)tensor * TELEMS_ + (size_t)plane * SIMG_;

  // Per-lane register twiddles (constant across all FFTs here)
  float2 tw[9];
  {
    float s, c;
    __sincosf(-6.283185307179586f * (float)r / 256.0f, &s, &c);
    tw[0] = make_float2(c, s); tw[1] = cmul(tw[0], tw[0]); tw[2] = cmul(tw[1], tw[0]);
    __sincosf(-6.283185307179586f * (float)(r & 15) / 64.0f, &s, &c);
    tw[3] = make_float2(c, s); tw[4] = cmul(tw[3], tw[3]); tw[5] = cmul(tw[4], tw[3]);
    __sincosf(-6.283185307179586f * (float)(r & 3) / 16.0f, &s, &c);
    tw[6] = make_float2(c, s); tw[7] = cmul(tw[6], tw[6]); tw[8] = cmul(tw[7], tw[6]);
  }
  // lane's low-6-bit frequency part m; mirror source lane rp
  int m = ((r & 3) << 4) | (((r >> 2) & 3) << 2) | (r >> 4);
  int mp = (64 - m) & 63;
  int rp = ((mp >> 4) & 3) | (((mp >> 2) & 3) << 2) | ((mp & 3) << 4);

  // ---- Row pass: 128 packed-real FFTs (image rows 2q,2q+1), 8 per wave ---
  for (int it = 0; it < 8; ++it) {
    int q = it * 16 + wv;               // pair index [0,128)
    const float* r0 = in + (size_t)(2 * q) * 256;
    float2 x[4]; unsigned u[4];
#pragma unroll
    for (int j = 0; j < 4; ++j)
      x[j] = make_float2(r0[r + 64 * j], r0[256 + r + 64 * j]);
    fft256_reg(x, u, r, tw);
    unsigned mir[4];
#pragma unroll
    for (int t = 0; t < 4; ++t) mir[t] = (unsigned)__shfl((int)u[t], rp, 64);
    float2 ZN = u2f(u[2]);              // lane 0: freq 128 (Nyquist)
    // Hermitian unpack; slots 0,1 give k = m, 64+m <= 127
#pragma unroll
    for (int s = 0; s < 2; ++s) {
      int k = 64 * s + m;               // for lane 0 s=0: k=0 -> packed row
      int sp = (m == 0) ? ((4 - s) & 3) : (3 - s);
      float2 Zk = u2f(u[s]), Zm = u2f(mir[sp]);
      bool pr = (m == 0) && (s == 0);
      float2 A  = make_float2(0.5f * (Zk.x + Zm.x), pr ? ZN.x : 0.5f * (Zk.y - Zm.y));
      float2 Bv = make_float2(0.5f * (Zk.y + Zm.y), pr ? ZN.y : 0.5f * (Zm.x - Zk.x));
      unsigned w32 = pk8<false>(A, 0u);
      w32 = pk8<true>(Bv, w32);
      S32[k * 128 + ((q + k) & 127)] = w32;   // rotation: 2-way banks (free)
    }
  }

  __syncthreads();                      // the ONE block barrier

  // ---- Column pass: FFT S row ell (8 per wave), direct global write ------
  for (int it = 0; it < 8; ++it) {
    int ell = it * 16 + wv;             // [0,128)
    const unsigned short* Sh = (const unsigned short*)S32;
    float2 x[4]; unsigned u[4];
#pragma unroll
    for (int j = 0; j < 4; ++j) {
      int c = r + 64 * j;               // slot = d3
      int e = ((((c >> 1) + ell) & 127) << 1) | (c & 1);
      x[j] = up8((unsigned)Sh[ell * 256 + e]);
    }
    fft256_reg(x, u, r, tw);
    if (ell == 0) {
      // packed row: unpack into output rows 0 (F0) and 128 (F128)
      unsigned mir[4];
#pragma unroll
      for (int t = 0; t < 4; ++t) mir[t] = (unsigned)__shfl((int)u[t], rp, 64);
      unsigned f0[4], f1[4];
#pragma unroll
      for (int s = 0; s < 4; ++s) {
        int sp = (m == 0) ? ((4 - s) & 3) : (3 - s);
        float2 Zk = u2f(u[s]), Zm = u2f(mir[sp]);
        f0[s] = f2u(make_float2(0.5f * (Zk.x + Zm.x), 0.5f * (Zk.y - Zm.y)));
        f1[s] = f2u(make_float2(0.5f * (Zk.y + Zm.y), 0.5f * (Zm.x - Zk.x)));
      }
      *(uint4*)(outp + 4 * r) = make_uint4(f0[0], f0[1], f0[2], f0[3]);
      *(uint4*)(outp + (size_t)128 * 256 + 4 * r) = make_uint4(f1[0], f1[1], f1[2], f1[3]);
    } else {
      // physical pos 4r+s holds freq 64s+m -- fixed within-row permutation, ok
      *(uint4*)(outp + (size_t)ell * 256 + 4 * r) = make_uint4(u[0], u[1], u[2], u[3]);
    }
  }
  if (wv >= 13) {                       // zero pad rows 129..131
    int c = 129 + (wv - 13);
    *(uint4*)(outp + (size_t)c * 256 + 4 * r) = make_uint4(0, 0, 0, 0);
  }
}

__device__ __forceinline__ float cab2(float2 v) { return v.x * v.x + v.y * v.y; }

// -------- Fused normalize + triplet distance, uint4-vectorized -------------
__global__ __launch_bounds__(256) void dist_kernel(const unsigned* __restrict__ af,
                                                   const unsigned* __restrict__ pf,
                                                   const unsigned* __restrict__ nf,
                                                   const int* __restrict__ neg,
                                                   float* __restrict__ acc) {
  int b = blockIdx.y;
  int j = (neg[1] == 0) ? (int)((const long long*)neg)[b * 2 + 1] : neg[b * 2 + 1];
  size_t ab = (size_t)b * TIMG_;
  size_t jb = (size_t)j * TIMG_;
  int t4 = blockIdx.x * 256 + threadIdx.x;   // [0, 8448)
  int flat0 = t4 * 4;                        // 4 consecutive elems, same k2 row
  int k2 = flat0 >> 8;
  float w = (k2 == 0 || k2 >= 128) ? 1.0f : 2.0f;

  unsigned A[3][4], P[3][4], N[3][4], M[3][4];
#pragma unroll
  for (int ch = 0; ch < 3; ++ch) {
    uint4 t;
    t = *(const uint4*)(af + ab + ch * SIMG_ + flat0); A[ch][0]=t.x; A[ch][1]=t.y; A[ch][2]=t.z; A[ch][3]=t.w;
    t = *(const uint4*)(pf + ab + ch * SIMG_ + flat0); P[ch][0]=t.x; P[ch][1]=t.y; P[ch][2]=t.z; P[ch][3]=t.w;
    t = *(const uint4*)(nf + ab + ch * SIMG_ + flat0); N[ch][0]=t.x; N[ch][1]=t.y; N[ch][2]=t.z; N[ch][3]=t.w;
    t = *(const uint4*)(nf + jb + ch * SIMG_ + flat0); M[ch][0]=t.x; M[ch][1]=t.y; M[ch][2]=t.z; M[ch][3]=t.w;
  }
  float s_ap = 0.0f, s_a0 = 0.0f, s_a1 = 0.0f;
#pragma unroll
  for (int e = 0; e < 4; ++e) {
    float2 a0 = u2f(A[0][e]), a1 = u2f(A[1][e]), a2 = u2f(A[2][e]);
    float2 p0 = u2f(P[0][e]), p1 = u2f(P[1][e]), p2 = u2f(P[2][e]);
    float2 n0 = u2f(N[0][e]), n1 = u2f(N[1][e]), n2 = u2f(N[2][e]);
    float2 m0 = u2f(M[0][e]), m1 = u2f(M[1][e]), m2 = u2f(M[2][e]);
    float sa = 0.01f / (sqrtf(cab2(a0) + cab2(a1) + cab2(a2)) + 1e-8f);
    float sp = 0.01f / (sqrtf(cab2(p0) + cab2(p1) + cab2(p2)) + 1e-8f);
    float sn = 0.01f / (sqrtf(cab2(n0) + cab2(n1) + cab2(n2)) + 1e-8f);
    float sm = 0.01f / (sqrtf(cab2(m0) + cab2(m1) + cab2(m2)) + 1e-8f);
    float dx, dy;
    dx = a0.x * sa - p0.x * sp; dy = a0.y * sa - p0.y * sp; s_ap += sqrtf(dx * dx + dy * dy);
    dx = a1.x * sa - p1.x * sp; dy = a1.y * sa - p1.y * sp; s_ap += sqrtf(dx * dx + dy * dy);
    dx = a2.x * sa - p2.x * sp; dy = a2.y * sa - p2.y * sp; s_ap += sqrtf(dx * dx + dy * dy);
    dx = a0.x * sa - n0.x * sn; dy = a0.y * sa - n0.y * sn; s_a0 += sqrtf(dx * dx + dy * dy);
    dx = a1.x * sa - n1.x * sn; dy = a1.y * sa - n1.y * sn; s_a0 += sqrtf(dx * dx + dy * dy);
    dx = a2.x * sa - n2.x * sn; dy = a2.y * sa - n2.y * sn; s_a0 += sqrtf(dx * dx + dy * dy);
    dx = a0.x * sa - m0.x * sm; dy = a0.y * sa - m0.y * sm; s_a1 += sqrtf(dx * dx + dy * dy);
    dx = a1.x * sa - m1.x * sm; dy = a1.y * sa - m1.y * sm; s_a1 += sqrtf(dx * dx + dy * dy);
    dx = a2.x * sa - m2.x * sm; dy = a2.y * sa - m2.y * sm; s_a1 += sqrtf(dx * dx + dy * dy);
  }
  s_ap *= w; s_a0 *= w; s_a1 *= w;
#pragma unroll
  for (int off = 32; off > 0; off >>= 1) {
    s_ap += __shfl_down(s_ap, off);
    s_a0 += __shfl_down(s_a0, off);
    s_a1 += __shfl_down(s_a1, off);
  }
  __shared__ float red[3][4];
  int lane = threadIdx.x & 63, wid = threadIdx.x >> 6;
  if (lane == 0) { red[0][wid] = s_ap; red[1][wid] = s_a0; red[2][wid] = s_a1; }
  __syncthreads();
  if (threadIdx.x == 0) {
    atomicAdd(&acc[b * 3 + 0], red[0][0] + red[0][1] + red[0][2] + red[0][3]);
    atomicAdd(&acc[b * 3 + 1], red[1][0] + red[1][1] + red[1][2] + red[1][3]);
    atomicAdd(&acc[b * 3 + 2], red[2][0] + red[2][1] + red[2][2] + red[2][3]);
  }
}

__global__ void zero_acc(float* acc) { acc[threadIdx.x] = 0.0f; }

__global__ void final_kernel(const float* __restrict__ acc, float* __restrict__ out) {
  int b = threadIdx.x;  // 64 threads
  const float inv = 1.0f / 196608.0f;  // C*H*W (full grid)
  float dap = acc[b * 3 + 0] * inv;
  float da0 = acc[b * 3 + 1] * inv;
  float da1 = acc[b * 3 + 2] * inv;
  float term = dap / (da0 + 1e-7f) + dap / (da1 + 1e-7f);
#pragma unroll
  for (int off = 32; off > 0; off >>= 1) term += __shfl_down(term, off);
  if (b == 0) out[0] = term * (1.0f / 128.0f);  // / (K*B)
}

extern "C" void kernel_launch(void* const* d_in, const int* in_sizes, int n_in,
                              void* d_out, int out_size, void* d_ws, size_t ws_size,
                              hipStream_t stream) {
  const float* a = (const float*)d_in[0];
  const float* p = (const float*)d_in[1];
  const float* n = (const float*)d_in[2];
  const int* neg = (const int*)d_in[3];
  float* out = (float*)d_out;

  unsigned* base = (unsigned*)d_ws;             // af | pf | nf, TELEMS_ each
  float* acc = (float*)(base + 3 * TELEMS_);    // ~74.3 MB + 768 B total

  zero_acc<<<1, 192, 0, stream>>>(acc);
  fft2_fused<<<576, 1024, 0, stream>>>(a, p, n, base);
  dist_kernel<<<dim3(33, 64), 256, 0, stream>>>(base, base + TELEMS_,
                                                base + 2 * TELEMS_, neg, acc);
  final_kernel<<<1, 64, 0, stream>>>(acc, out);
}